// Round 4
// baseline (395.697 us; speedup 1.0000x reference)
//
#include <hip/hip_runtime.h>
#include <hip/hip_bf16.h>
#include <stdint.h>

#define DIM 128
#define ODIM 64
#define BM 128
#define BN 64

typedef __attribute__((ext_vector_type(8))) __bf16 bf16x8;
typedef __attribute__((ext_vector_type(4))) __bf16 bf16x4;
typedef __attribute__((ext_vector_type(2))) __bf16 bf16x2;
typedef __attribute__((ext_vector_type(4))) float f32x4;

#define MFMA_K32(a, b, c) __builtin_amdgcn_mfma_f32_16x16x32_bf16((a), (b), (c), 0, 0, 0)
#define MFMA_K16(a, b, c) __builtin_amdgcn_mfma_f32_16x16x16bf16_1k((a), (b), (c), 0, 0, 0)

// k = exp(-dist/(2*co)) = 2^(-sqrt(C2D*d2)), C2D = (log2e/(2*co))^2 pre-applied to x2/t2.
#define RBFD 10.077141124806595
#define LOG2E 1.4426950408889634
#define C2D ((LOG2E / (2.0 * RBFD)) * (LOG2E / (2.0 * RBFD)))

__device__ __forceinline__ void async_copy16(const void* g, void* l) {
  __builtin_amdgcn_global_load_lds((const __attribute__((address_space(1))) void*)g,
                                   (__attribute__((address_space(3))) void*)l, 16, 0, 0);
}
__device__ __forceinline__ void async_copy4(const void* g, void* l) {
  __builtin_amdgcn_global_load_lds((const __attribute__((address_space(1))) void*)g,
                                   (__attribute__((address_space(3))) void*)l, 4, 0, 0);
}

// bf16 pack: returns dword with lo16=bf16(a), hi16=bf16(b) (round-half-up)
__device__ __forceinline__ uint32_t pack_bf16(float a, float b) {
  uint32_t ua = __builtin_bit_cast(uint32_t, a) + 0x8000u;
  uint32_t ub = __builtin_bit_cast(uint32_t, b) + 0x8000u;
  return __builtin_amdgcn_perm(ub, ua, 0x07060302u);
}

// ---- Fused prepass (one launch): train->bf16+norms | features->bf16+norms | W transpose.
__global__ void prep_all(const float* __restrict__ train, __bf16* __restrict__ Tb,
                         float* __restrict__ t2, const float* __restrict__ feat,
                         __bf16* __restrict__ Fb, float* __restrict__ x2,
                         const float* __restrict__ W, __bf16* __restrict__ Wt,
                         int Ntrain, int Npad, int nFeat, int tB, int fB, float scale) {
  __shared__ float tile[64][65];
  int b = blockIdx.x;
  int t = threadIdx.x;
  if (b < tB + fB) {
    const float* src;
    __bf16* dst;
    float* sq;
    int nValid, nPad, row0;
    float padv;
    if (b < tB) {
      src = train; dst = Tb; sq = t2; nValid = Ntrain; nPad = Npad; row0 = b * 4; padv = 1e30f;
    } else {
      src = feat; dst = Fb; sq = x2; nValid = nFeat; nPad = nFeat; row0 = (b - tB) * 4; padv = 0.0f;
    }
    int row = row0 + (t >> 6);
    int lane = t & 63;
    if (row >= nPad) return;
    float2 v = make_float2(0.0f, 0.0f);
    if (row < nValid) v = ((const float2*)src)[(size_t)row * 64 + lane];
    bf16x2 p;
    p.x = (__bf16)v.x;
    p.y = (__bf16)v.y;
    *(bf16x2*)&dst[(size_t)row * DIM + lane * 2] = p;
    float ss = v.x * v.x + v.y * v.y;
    #pragma unroll
    for (int off = 32; off > 0; off >>= 1) ss += __shfl_down(ss, off);
    if (lane == 0) sq[row] = (row < nValid) ? ss * scale : padv;
    return;
  }
  int j0 = (b - tB - fB) * 64;
  int jr = t >> 2;
  int cg = (t & 3) * 16;
  int j = j0 + jr;
  if (j < Ntrain) {
    const float4* src = (const float4*)(W + (size_t)j * ODIM);
    #pragma unroll
    for (int q = 0; q < 4; ++q) {
      float4 u = src[(cg >> 2) + q];
      tile[jr][cg + q * 4 + 0] = u.x;
      tile[jr][cg + q * 4 + 1] = u.y;
      tile[jr][cg + q * 4 + 2] = u.z;
      tile[jr][cg + q * 4 + 3] = u.w;
    }
  } else {
    #pragma unroll
    for (int q = 0; q < 16; ++q) tile[jr][cg + q] = 0.0f;
  }
  __syncthreads();
  int v = t >> 2;
  int jc = (t & 3) * 16;
  __bf16 ob[16];
  #pragma unroll
  for (int q = 0; q < 16; ++q) ob[q] = (__bf16)tile[jc + q][v];
  __bf16* dst = Wt + (size_t)v * Npad + j0 + jc;
  *(bf16x8*)dst = *(bf16x8*)&ob[0];
  *(bf16x8*)(dst + 8) = *(bf16x8*)&ob[8];
}

// ---- Main fused kernel (S^T formulation, P chained in registers).
// grid(NS, 16): blockIdx.x = ns (fastest) so same-chunk readers (same ns, all mb)
// are NS apart in linear id; NS % 8 == 0 keeps them co-XCD for L2 reuse of T.
template <int NS, bool ATOMIC>
__global__ __launch_bounds__(256, 6) void rbf_main(
    const __bf16* __restrict__ Fb, const __bf16* __restrict__ Tb,
    const __bf16* __restrict__ Wt, const float* __restrict__ t2g,
    const float* __restrict__ x2g, float* __restrict__ outOrPart,
    int nRows, int Npad, int nChunks) {
  __shared__ __bf16 sT[BN * DIM];   // 16 KB, XOR-swizzled 16B granules
  __shared__ __bf16 sW[ODIM * BN];  // 8 KB, XOR-swizzled 16B granules
  __shared__ float st2[BN];

  const int tid = threadIdx.x;
  const int wave = tid >> 6;
  const int lane = tid & 63;
  const int l16 = lane & 15;
  const int g4 = lane >> 4;

  const int ns = (int)blockIdx.x;  // 0..NS-1
  const int mb = (int)blockIdx.y;  // 0..15

  constexpr float KNEG2 = (float)(-2.0 * C2D);

  // ---- chunk-invariant LDS read offsets (hoisted; ds_read gets reg + imm form)
  int aOff[4];  // sT A-frags: + mt*4096 imm
  #pragma unroll
  for (int ko = 0; ko < 4; ++ko) aOff[ko] = l16 * 256 + (((ko * 4 + g4) ^ l16) << 4);
  int wOff[4];  // sW B-frags: + vi*2048 imm
  #pragma unroll
  for (int mt = 0; mt < 4; ++mt)
    wOff[mt] = l16 * 128 + ((g4 & 1) << 3) + ((((2 * mt + (g4 >> 1)) ^ (l16 & 7))) << 4);

  // ---- chunk-invariant staging offsets; global bases advance by stride per chunk
  int tGOff[4], ldsOffT[4];
  #pragma unroll
  for (int i = 0; i < 4; ++i) {
    int off = i * 4096 + wave * 1024;
    int loff = off + lane * 16;
    int row = loff >> 8;
    int gran = (loff >> 4) & 15;
    ldsOffT[i] = off;
    tGOff[i] = row * 256 + ((gran ^ (row & 15)) << 4);
  }
  int wGOff[2], ldsOffW[2];
  #pragma unroll
  for (int i = 0; i < 2; ++i) {
    int off = i * 4096 + wave * 1024;
    int loff = off + lane * 16;
    int v = loff >> 7;
    int gran = (loff >> 4) & 7;
    ldsOffW[i] = off;
    wGOff[i] = v * (Npad * 2) + ((gran ^ (v & 7)) << 4);
  }
  const char* gTbase = (const char*)Tb + (size_t)ns * (BN * 256);
  const char* gWbase = (const char*)Wt + (size_t)ns * (BN * 2);
  const char* gt2 = (const char*)(t2g) + (size_t)ns * (BN * 4) + lane * 4;
  const size_t strT = (size_t)NS * (BN * 256);
  const size_t strW = (size_t)NS * (BN * 2);
  const size_t str2 = (size_t)NS * (BN * 4);

  // F fragments (chunk-invariant)
  bf16x8 bF[2][4];
  #pragma unroll
  for (int nf = 0; nf < 2; ++nf)
    #pragma unroll
    for (int ko = 0; ko < 4; ++ko)
      bF[nf][ko] = *(const bf16x8*)(Fb + ((size_t)(mb * BM + wave * 32 + nf * 16 + l16)) * DIM +
                                    ko * 32 + g4 * 8);
  float x2v[2];
  #pragma unroll
  for (int nf = 0; nf < 2; ++nf)
    x2v[nf] = x2g[mb * BM + wave * 32 + nf * 16 + l16];

  f32x4 zero4 = {0.0f, 0.0f, 0.0f, 0.0f};
  f32x4 oacc[2][4];
  #pragma unroll
  for (int nf = 0; nf < 2; ++nf)
    #pragma unroll
    for (int vi = 0; vi < 4; ++vi) oacc[nf][vi] = zero4;

  for (int c = ns; c < nChunks; c += NS) {
    #pragma unroll
    for (int i = 0; i < 4; ++i) async_copy16(gTbase + tGOff[i], (char*)sT + ldsOffT[i]);
    #pragma unroll
    for (int i = 0; i < 2; ++i) async_copy16(gWbase + wGOff[i], (char*)sW + ldsOffW[i]);
    if (wave == 0) async_copy4(gt2, (char*)st2);
    gTbase += strT;
    gWbase += strW;
    gt2 += str2;
    __syncthreads();

    // S^T per 16-train tile mt, elementwise, pack to A-frags in registers
    uint2 pk[4][2];
    #pragma unroll
    for (int mt = 0; mt < 4; ++mt) {
      f32x4 s0 = zero4, s1 = zero4;
      #pragma unroll
      for (int ko = 0; ko < 4; ++ko) {
        bf16x8 a = *(const bf16x8*)((const char*)sT + aOff[ko] + mt * 4096);
        s0 = MFMA_K32(a, bF[0][ko], s0);
        s1 = MFMA_K32(a, bF[1][ko], s1);
      }
      f32x4 t2v = *(const f32x4*)&st2[mt * 16 + g4 * 4];
      float kv0[4], kv1[4];
      #pragma unroll
      for (int r = 0; r < 4; ++r) {
        float d20 = __builtin_fmaf(KNEG2, s0[r], t2v[r] + x2v[0]);
        float d21 = __builtin_fmaf(KNEG2, s1[r], t2v[r] + x2v[1]);
        kv0[r] = __builtin_amdgcn_exp2f(-__builtin_amdgcn_sqrtf(d20));
        kv1[r] = __builtin_amdgcn_exp2f(-__builtin_amdgcn_sqrtf(d21));
      }
      pk[mt][0] = make_uint2(pack_bf16(kv0[0], kv0[1]), pack_bf16(kv0[2], kv0[3]));
      pk[mt][1] = make_uint2(pack_bf16(kv1[0], kv1[1]), pack_bf16(kv1[2], kv1[3]));
    }

    // O += P·W via K16 MFMA, A from registers, B from sW
    #pragma unroll
    for (int vi = 0; vi < 4; ++vi) {
      #pragma unroll
      for (int mt = 0; mt < 4; ++mt) {
        bf16x4 wf = *(const bf16x4*)((const char*)sW + wOff[mt] + vi * 2048);
        oacc[0][vi] = MFMA_K16(__builtin_bit_cast(bf16x4, pk[mt][0]), wf, oacc[0][vi]);
        oacc[1][vi] = MFMA_K16(__builtin_bit_cast(bf16x4, pk[mt][1]), wf, oacc[1][vi]);
      }
    }
    __syncthreads();  // protect sT/sW from next chunk's staging
  }

  if (ATOMIC) {
    float* out = outOrPart;
    #pragma unroll
    for (int nf = 0; nf < 2; ++nf)
      #pragma unroll
      for (int vi = 0; vi < 4; ++vi)
        #pragma unroll
        for (int r = 0; r < 4; ++r) {
          int row = mb * BM + wave * 32 + nf * 16 + g4 * 4 + r;
          int col = vi * 16 + l16;
          atomicAdd(&out[(size_t)row * ODIM + col], oacc[nf][vi][r]);
        }
  } else {
    float* dst = outOrPart + (size_t)ns * (size_t)nRows * ODIM;
    #pragma unroll
    for (int nf = 0; nf < 2; ++nf)
      #pragma unroll
      for (int vi = 0; vi < 4; ++vi)
        #pragma unroll
        for (int r = 0; r < 4; ++r) {
          int row = mb * BM + wave * 32 + nf * 16 + g4 * 4 + r;
          int col = vi * 16 + l16;
          dst[(size_t)row * ODIM + col] = oacc[nf][vi][r];
        }
  }
}

template <int NS>
__global__ void reduce_parts(const float4* __restrict__ part, float4* __restrict__ out,
                             int total4) {
  int i = (int)blockIdx.x * blockDim.x + threadIdx.x;
  if (i >= total4) return;
  float4 s = make_float4(0.0f, 0.0f, 0.0f, 0.0f);
  #pragma unroll
  for (int sp = 0; sp < NS; ++sp) {
    float4 v = part[(size_t)sp * total4 + i];
    s.x += v.x; s.y += v.y; s.z += v.z; s.w += v.w;
  }
  out[i] = s;
}

extern "C" void kernel_launch(void* const* d_in, const int* in_sizes, int n_in,
                              void* d_out, int out_size, void* d_ws, size_t ws_size,
                              hipStream_t stream) {
  (void)n_in;
  const float* features = (const float*)d_in[0];
  const float* train = (const float*)d_in[1];
  const float* weights = (const float*)d_in[2];
  float* out = (float*)d_out;

  const int n = in_sizes[0] / DIM;        // 2048
  const int N = in_sizes[1] / DIM;        // 50000
  const int Npad = ((N + 63) / 64) * 64;  // 50048
  const int nChunks = Npad / 64;          // 782

  size_t off = 0;
  auto alloc = [&](size_t bytes) {
    size_t o = off;
    off = (off + bytes + 255) & ~(size_t)255;
    return o;
  };
  size_t oT = alloc((size_t)Npad * DIM * 2);
  size_t oW = alloc((size_t)ODIM * Npad * 2);
  size_t oF = alloc((size_t)n * DIM * 2);
  size_t ot2 = alloc((size_t)Npad * 4);
  size_t ox2 = alloc((size_t)n * 4);
  size_t bufEnd = off;
  size_t oPart = alloc(0);  // partials start here

  char* ws = (char*)d_ws;
  __bf16* Tb = (__bf16*)(ws + oT);
  __bf16* Wt = (__bf16*)(ws + oW);
  __bf16* Fb = (__bf16*)(ws + oF);
  float* t2 = (float*)(ws + ot2);
  float* x2 = (float*)(ws + ox2);
  float* part = (float*)(ws + oPart);

  const int tB = Npad / 4;
  const int fB = n / 4;
  const int wB = Npad / 64;
  prep_all<<<tB + fB + wB, 256, 0, stream>>>(train, Tb, t2, features, Fb, x2, weights, Wt,
                                             N, Npad, n, tB, fB, (float)C2D);

  const int mBlocks = n / BM;  // 16
  const int total4 = n * ODIM / 4;
  const size_t partBytes = (size_t)n * ODIM * 4;

  if (ws_size >= bufEnd + 96 * partBytes) {
    rbf_main<96, false><<<dim3(96, mBlocks), 256, 0, stream>>>(Fb, Tb, Wt, t2, x2, part, n,
                                                               Npad, nChunks);
    reduce_parts<96><<<(total4 + 255) / 256, 256, 0, stream>>>((const float4*)part,
                                                               (float4*)out, total4);
  } else if (ws_size >= bufEnd + 32 * partBytes) {
    rbf_main<32, false><<<dim3(32, mBlocks), 256, 0, stream>>>(Fb, Tb, Wt, t2, x2, part, n,
                                                               Npad, nChunks);
    reduce_parts<32><<<(total4 + 255) / 256, 256, 0, stream>>>((const float4*)part,
                                                               (float4*)out, total4);
  } else {
    hipMemsetAsync(d_out, 0, (size_t)out_size * sizeof(float), stream);
    rbf_main<96, true><<<dim3(96, mBlocks), 256, 0, stream>>>(Fb, Tb, Wt, t2, x2, out, n,
                                                              Npad, nChunks);
  }
}

// Round 5
// 206.026 us; speedup vs baseline: 1.9206x; 1.9206x over previous
//
#include <hip/hip_runtime.h>
#include <hip/hip_bf16.h>
#include <stdint.h>

#define DIM 128
#define ODIM 64
#define BM 128
#define BN 64

typedef __attribute__((ext_vector_type(8))) __bf16 bf16x8;
typedef __attribute__((ext_vector_type(4))) __bf16 bf16x4;
typedef __attribute__((ext_vector_type(2))) __bf16 bf16x2;
typedef __attribute__((ext_vector_type(4))) float f32x4;

#define MFMA_K32(a, b, c) __builtin_amdgcn_mfma_f32_16x16x32_bf16((a), (b), (c), 0, 0, 0)
#define MFMA_K16(a, b, c) __builtin_amdgcn_mfma_f32_16x16x16bf16_1k((a), (b), (c), 0, 0, 0)

// k = exp(-dist/(2*co)) = 2^(-sqrt(C2D*d2)), C2D = (log2e/(2*co))^2 pre-applied to x2/t2.
#define RBFD 10.077141124806595
#define LOG2E 1.4426950408889634
#define C2D ((LOG2E / (2.0 * RBFD)) * (LOG2E / (2.0 * RBFD)))

__device__ __forceinline__ void async_copy16(const void* g, void* l) {
  __builtin_amdgcn_global_load_lds((const __attribute__((address_space(1))) void*)g,
                                   (__attribute__((address_space(3))) void*)l, 16, 0, 0);
}

// bf16 pack: returns dword with lo16=bf16(a), hi16=bf16(b) (round-half-up)
__device__ __forceinline__ uint32_t pack_bf16(float a, float b) {
  uint32_t ua = __builtin_bit_cast(uint32_t, a) + 0x8000u;
  uint32_t ub = __builtin_bit_cast(uint32_t, b) + 0x8000u;
  return __builtin_amdgcn_perm(ub, ua, 0x07060302u);
}

// ---- Fused prepass (one launch): train->bf16+norms | features->bf16+norms | W transpose.
__global__ void prep_all(const float* __restrict__ train, __bf16* __restrict__ Tb,
                         float* __restrict__ t2, const float* __restrict__ feat,
                         __bf16* __restrict__ Fb, float* __restrict__ x2,
                         const float* __restrict__ W, __bf16* __restrict__ Wt,
                         int Ntrain, int Npad, int nFeat, int tB, int fB, float scale) {
  __shared__ float tile[64][65];
  int b = blockIdx.x;
  int t = threadIdx.x;
  if (b < tB + fB) {
    const float* src;
    __bf16* dst;
    float* sq;
    int nValid, nPad, row0;
    float padv;
    if (b < tB) {
      src = train; dst = Tb; sq = t2; nValid = Ntrain; nPad = Npad; row0 = b * 4; padv = 1e30f;
    } else {
      src = feat; dst = Fb; sq = x2; nValid = nFeat; nPad = nFeat; row0 = (b - tB) * 4; padv = 0.0f;
    }
    int row = row0 + (t >> 6);
    int lane = t & 63;
    if (row >= nPad) return;
    float2 v = make_float2(0.0f, 0.0f);
    if (row < nValid) v = ((const float2*)src)[(size_t)row * 64 + lane];
    bf16x2 p;
    p.x = (__bf16)v.x;
    p.y = (__bf16)v.y;
    *(bf16x2*)&dst[(size_t)row * DIM + lane * 2] = p;
    float ss = v.x * v.x + v.y * v.y;
    #pragma unroll
    for (int off = 32; off > 0; off >>= 1) ss += __shfl_down(ss, off);
    if (lane == 0) sq[row] = (row < nValid) ? ss * scale : padv;
    return;
  }
  int j0 = (b - tB - fB) * 64;
  int jr = t >> 2;
  int cg = (t & 3) * 16;
  int j = j0 + jr;
  if (j < Ntrain) {
    const float4* src = (const float4*)(W + (size_t)j * ODIM);
    #pragma unroll
    for (int q = 0; q < 4; ++q) {
      float4 u = src[(cg >> 2) + q];
      tile[jr][cg + q * 4 + 0] = u.x;
      tile[jr][cg + q * 4 + 1] = u.y;
      tile[jr][cg + q * 4 + 2] = u.z;
      tile[jr][cg + q * 4 + 3] = u.w;
    }
  } else {
    #pragma unroll
    for (int q = 0; q < 16; ++q) tile[jr][cg + q] = 0.0f;
  }
  __syncthreads();
  int v = t >> 2;
  int jc = (t & 3) * 16;
  __bf16 ob[16];
  #pragma unroll
  for (int q = 0; q < 16; ++q) ob[q] = (__bf16)tile[jc + q][v];
  __bf16* dst = Wt + (size_t)v * Npad + j0 + jc;
  *(bf16x8*)dst = *(bf16x8*)&ob[0];
  *(bf16x8*)(dst + 8) = *(bf16x8*)&ob[8];
}

// ---- Main fused kernel.
// Double-buffered sT (2x16 KB LDS, no sW/st2: W B-frags and t2 come straight from
// global/L2). Stage chunk c+1 BEFORE computing chunk c, so the compiler's
// vmcnt(0)-drain before s_barrier overlaps with ~10k cycles of compute.
// grid(NS, 16), ns fastest; NS % 8 == 0 keeps same-chunk readers co-XCD.
template <int NS, bool ATOMIC>
__global__ __launch_bounds__(256, 4) void rbf_main(
    const __bf16* __restrict__ Fb, const __bf16* __restrict__ Tb,
    const __bf16* __restrict__ Wt, const float* __restrict__ t2g,
    const float* __restrict__ x2g, float* __restrict__ outOrPart,
    int nRows, int Npad, int nChunks) {
  __shared__ __bf16 sT[2][BN * DIM];  // 2 x 16 KB, XOR-swizzled 16B granules

  const int tid = threadIdx.x;
  const int wave = tid >> 6;
  const int lane = tid & 63;
  const int l16 = lane & 15;
  const int g4 = lane >> 4;

  const int ns = (int)blockIdx.x;  // 0..NS-1
  const int mb = (int)blockIdx.y;  // 0..15

  constexpr float KNEG2 = (float)(-2.0 * C2D);

  // chunk-invariant LDS read offsets for sT A-frags (+ mt*4096 + buf*16384 imm/reg)
  int aOff[4];
  #pragma unroll
  for (int ko = 0; ko < 4; ++ko) aOff[ko] = l16 * 256 + (((ko * 4 + g4) ^ l16) << 4);

  // chunk-invariant staging offsets (LDS side wave-uniform; global side per-lane gather)
  int tGOff[4], ldsOffT[4];
  #pragma unroll
  for (int i = 0; i < 4; ++i) {
    int off = i * 4096 + wave * 1024;
    int loff = off + lane * 16;
    int row = loff >> 8;
    int gran = (loff >> 4) & 15;
    ldsOffT[i] = off;
    tGOff[i] = row * 256 + ((gran ^ (row & 15)) << 4);
  }
  const char* gTbase = (const char*)Tb + (size_t)ns * (BN * 256);
  const size_t strT = (size_t)NS * (BN * 256);

  // W row pointers (per vi) and t2 pointer — bumped per chunk, loads are L2-hits.
  const __bf16* wPtr[4];
  #pragma unroll
  for (int vi = 0; vi < 4; ++vi)
    wPtr[vi] = Wt + (size_t)(vi * 16 + l16) * Npad + (size_t)ns * BN + g4 * 4;
  const float* t2p = t2g + (size_t)ns * BN + g4 * 4;

  // F fragments (chunk-invariant)
  bf16x8 bF[2][4];
  #pragma unroll
  for (int nf = 0; nf < 2; ++nf)
    #pragma unroll
    for (int ko = 0; ko < 4; ++ko)
      bF[nf][ko] = *(const bf16x8*)(Fb + ((size_t)(mb * BM + wave * 32 + nf * 16 + l16)) * DIM +
                                    ko * 32 + g4 * 8);
  float x2v[2];
  #pragma unroll
  for (int nf = 0; nf < 2; ++nf)
    x2v[nf] = x2g[mb * BM + wave * 32 + nf * 16 + l16];

  f32x4 zero4 = {0.0f, 0.0f, 0.0f, 0.0f};
  f32x4 oacc[2][4];
  #pragma unroll
  for (int nf = 0; nf < 2; ++nf)
    #pragma unroll
    for (int vi = 0; vi < 4; ++vi) oacc[nf][vi] = zero4;

  // prologue: stage first chunk into buf 0
  #pragma unroll
  for (int i = 0; i < 4; ++i) async_copy16(gTbase + tGOff[i], (char*)sT[0] + ldsOffT[i]);
  gTbase += strT;
  __syncthreads();

  int buf = 0;
  for (int c = ns;;) {
    int next = c + NS;
    if (next < nChunks) {  // stage next chunk into the other buffer (overlaps compute)
      #pragma unroll
      for (int i = 0; i < 4; ++i)
        async_copy16(gTbase + tGOff[i], (char*)sT[buf ^ 1] + ldsOffT[i]);
      gTbase += strT;
    }

    // S^T per 16-train tile mt, elementwise, pack to K16 A-frags in registers
    const char* sTb = (const char*)sT[buf];
    uint2 pk[4][2];
    #pragma unroll
    for (int mt = 0; mt < 4; ++mt) {
      f32x4 s0 = zero4, s1 = zero4;
      #pragma unroll
      for (int ko = 0; ko < 4; ++ko) {
        bf16x8 a = *(const bf16x8*)(sTb + aOff[ko] + mt * 4096);
        s0 = MFMA_K32(a, bF[0][ko], s0);
        s1 = MFMA_K32(a, bF[1][ko], s1);
      }
      f32x4 t2v = *(const f32x4*)(t2p + mt * 16);  // L2-hit, 16B, broadcast per g4 group
      float kv0[4], kv1[4];
      #pragma unroll
      for (int r = 0; r < 4; ++r) {
        float d20 = __builtin_fmaf(KNEG2, s0[r], t2v[r] + x2v[0]);
        float d21 = __builtin_fmaf(KNEG2, s1[r], t2v[r] + x2v[1]);
        kv0[r] = __builtin_amdgcn_exp2f(-__builtin_amdgcn_sqrtf(d20));
        kv1[r] = __builtin_amdgcn_exp2f(-__builtin_amdgcn_sqrtf(d21));
      }
      pk[mt][0] = make_uint2(pack_bf16(kv0[0], kv0[1]), pack_bf16(kv0[2], kv0[3]));
      pk[mt][1] = make_uint2(pack_bf16(kv1[0], kv1[1]), pack_bf16(kv1[2], kv1[3]));
    }

    // O += P·W via K16 MFMA; B-frags (8B) straight from global/L2.
    #pragma unroll
    for (int vi = 0; vi < 4; ++vi) {
      #pragma unroll
      for (int mt = 0; mt < 4; ++mt) {
        bf16x4 wf = *(const bf16x4*)(wPtr[vi] + mt * 16);
        oacc[0][vi] = MFMA_K16(__builtin_bit_cast(bf16x4, pk[mt][0]), wf, oacc[0][vi]);
        oacc[1][vi] = MFMA_K16(__builtin_bit_cast(bf16x4, pk[mt][1]), wf, oacc[1][vi]);
      }
    }
    #pragma unroll
    for (int vi = 0; vi < 4; ++vi) wPtr[vi] += NS * BN;
    t2p += NS * BN;

    __syncthreads();  // all waves done reading sT[buf]; staging of sT[buf^1] drained
    if (next >= nChunks) break;
    c = next;
    buf ^= 1;
  }

  if (ATOMIC) {
    float* out = outOrPart;
    #pragma unroll
    for (int nf = 0; nf < 2; ++nf)
      #pragma unroll
      for (int vi = 0; vi < 4; ++vi)
        #pragma unroll
        for (int r = 0; r < 4; ++r) {
          int row = mb * BM + wave * 32 + nf * 16 + g4 * 4 + r;
          int col = vi * 16 + l16;
          atomicAdd(&out[(size_t)row * ODIM + col], oacc[nf][vi][r]);
        }
  } else {
    float* dst = outOrPart + (size_t)ns * (size_t)nRows * ODIM;
    #pragma unroll
    for (int nf = 0; nf < 2; ++nf)
      #pragma unroll
      for (int vi = 0; vi < 4; ++vi)
        #pragma unroll
        for (int r = 0; r < 4; ++r) {
          int row = mb * BM + wave * 32 + nf * 16 + g4 * 4 + r;
          int col = vi * 16 + l16;
          dst[(size_t)row * ODIM + col] = oacc[nf][vi][r];
        }
  }
}

template <int NS>
__global__ void reduce_parts(const float4* __restrict__ part, float4* __restrict__ out,
                             int total4) {
  int i = (int)blockIdx.x * blockDim.x + threadIdx.x;
  if (i >= total4) return;
  float4 s = make_float4(0.0f, 0.0f, 0.0f, 0.0f);
  #pragma unroll
  for (int sp = 0; sp < NS; ++sp) {
    float4 v = part[(size_t)sp * total4 + i];
    s.x += v.x; s.y += v.y; s.z += v.z; s.w += v.w;
  }
  out[i] = s;
}

extern "C" void kernel_launch(void* const* d_in, const int* in_sizes, int n_in,
                              void* d_out, int out_size, void* d_ws, size_t ws_size,
                              hipStream_t stream) {
  (void)n_in;
  const float* features = (const float*)d_in[0];
  const float* train = (const float*)d_in[1];
  const float* weights = (const float*)d_in[2];
  float* out = (float*)d_out;

  const int n = in_sizes[0] / DIM;        // 2048
  const int N = in_sizes[1] / DIM;        // 50000
  const int Npad = ((N + 63) / 64) * 64;  // 50048
  const int nChunks = Npad / 64;          // 782

  size_t off = 0;
  auto alloc = [&](size_t bytes) {
    size_t o = off;
    off = (off + bytes + 255) & ~(size_t)255;
    return o;
  };
  size_t oT = alloc((size_t)Npad * DIM * 2);
  size_t oW = alloc((size_t)ODIM * Npad * 2);
  size_t oF = alloc((size_t)n * DIM * 2);
  size_t ot2 = alloc((size_t)Npad * 4);
  size_t ox2 = alloc((size_t)n * 4);
  size_t bufEnd = off;
  size_t oPart = alloc(0);

  char* ws = (char*)d_ws;
  __bf16* Tb = (__bf16*)(ws + oT);
  __bf16* Wt = (__bf16*)(ws + oW);
  __bf16* Fb = (__bf16*)(ws + oF);
  float* t2 = (float*)(ws + ot2);
  float* x2 = (float*)(ws + ox2);
  float* part = (float*)(ws + oPart);

  const int tB = Npad / 4;
  const int fB = n / 4;
  const int wB = Npad / 64;
  prep_all<<<tB + fB + wB, 256, 0, stream>>>(train, Tb, t2, features, Fb, x2, weights, Wt,
                                             N, Npad, n, tB, fB, (float)C2D);

  const int mBlocks = n / BM;  // 16
  const int total4 = n * ODIM / 4;
  const size_t partBytes = (size_t)n * ODIM * 4;

  if (ws_size >= bufEnd + 64 * partBytes) {
    rbf_main<64, false><<<dim3(64, mBlocks), 256, 0, stream>>>(Fb, Tb, Wt, t2, x2, part, n,
                                                               Npad, nChunks);
    reduce_parts<64><<<(total4 + 255) / 256, 256, 0, stream>>>((const float4*)part,
                                                               (float4*)out, total4);
  } else if (ws_size >= bufEnd + 32 * partBytes) {
    rbf_main<32, false><<<dim3(32, mBlocks), 256, 0, stream>>>(Fb, Tb, Wt, t2, x2, part, n,
                                                               Npad, nChunks);
    reduce_parts<32><<<(total4 + 255) / 256, 256, 0, stream>>>((const float4*)part,
                                                               (float4*)out, total4);
  } else {
    hipMemsetAsync(d_out, 0, (size_t)out_size * sizeof(float), stream);
    rbf_main<64, true><<<dim3(64, mBlocks), 256, 0, stream>>>(Fb, Tb, Wt, t2, x2, out, n,
                                                              Npad, nChunks);
  }
}

// Round 6
// 148.542 us; speedup vs baseline: 2.6639x; 1.3870x over previous
//
#include <hip/hip_runtime.h>
#include <hip/hip_bf16.h>
#include <stdint.h>

#define DIM 128
#define ODIM 64
#define BM 128
#define BN 64

typedef __attribute__((ext_vector_type(8))) __bf16 bf16x8;
typedef __attribute__((ext_vector_type(4))) __bf16 bf16x4;
typedef __attribute__((ext_vector_type(2))) __bf16 bf16x2;
typedef __attribute__((ext_vector_type(4))) float f32x4;

#define MFMA_K32(a, b, c) __builtin_amdgcn_mfma_f32_16x16x32_bf16((a), (b), (c), 0, 0, 0)
#define MFMA_K16(a, b, c) __builtin_amdgcn_mfma_f32_16x16x16bf16_1k((a), (b), (c), 0, 0, 0)

// k = exp(-dist/(2*co)) = 2^(-sqrt(C2D*d2)), C2D = (log2e/(2*co))^2 pre-applied to x2/t2.
#define RBFD 10.077141124806595
#define LOG2E 1.4426950408889634
#define C2D ((LOG2E / (2.0 * RBFD)) * (LOG2E / (2.0 * RBFD)))

__device__ __forceinline__ void async_copy16(const void* g, void* l) {
  __builtin_amdgcn_global_load_lds((const __attribute__((address_space(1))) void*)g,
                                   (__attribute__((address_space(3))) void*)l, 16, 0, 0);
}
__device__ __forceinline__ void async_copy4(const void* g, void* l) {
  __builtin_amdgcn_global_load_lds((const __attribute__((address_space(1))) void*)g,
                                   (__attribute__((address_space(3))) void*)l, 4, 0, 0);
}

// bf16 pack: returns dword with lo16=bf16(a), hi16=bf16(b) (round-half-up)
__device__ __forceinline__ uint32_t pack_bf16(float a, float b) {
  uint32_t ua = __builtin_bit_cast(uint32_t, a) + 0x8000u;
  uint32_t ub = __builtin_bit_cast(uint32_t, b) + 0x8000u;
  return __builtin_amdgcn_perm(ub, ua, 0x07060302u);
}

// ---- Fused prepass (one launch): train->bf16+norms | features->bf16+norms | W transpose.
__global__ void prep_all(const float* __restrict__ train, __bf16* __restrict__ Tb,
                         float* __restrict__ t2, const float* __restrict__ feat,
                         __bf16* __restrict__ Fb, float* __restrict__ x2,
                         const float* __restrict__ W, __bf16* __restrict__ Wt,
                         int Ntrain, int Npad, int nFeat, int tB, int fB, float scale) {
  __shared__ float tile[64][65];
  int b = blockIdx.x;
  int t = threadIdx.x;
  if (b < tB + fB) {
    const float* src;
    __bf16* dst;
    float* sq;
    int nValid, nPad, row0;
    float padv;
    if (b < tB) {
      src = train; dst = Tb; sq = t2; nValid = Ntrain; nPad = Npad; row0 = b * 4; padv = 1e30f;
    } else {
      src = feat; dst = Fb; sq = x2; nValid = nFeat; nPad = nFeat; row0 = (b - tB) * 4; padv = 0.0f;
    }
    int row = row0 + (t >> 6);
    int lane = t & 63;
    if (row >= nPad) return;
    float2 v = make_float2(0.0f, 0.0f);
    if (row < nValid) v = ((const float2*)src)[(size_t)row * 64 + lane];
    bf16x2 p;
    p.x = (__bf16)v.x;
    p.y = (__bf16)v.y;
    *(bf16x2*)&dst[(size_t)row * DIM + lane * 2] = p;
    float ss = v.x * v.x + v.y * v.y;
    #pragma unroll
    for (int off = 32; off > 0; off >>= 1) ss += __shfl_down(ss, off);
    if (lane == 0) sq[row] = (row < nValid) ? ss * scale : padv;
    return;
  }
  int j0 = (b - tB - fB) * 64;
  int jr = t >> 2;
  int cg = (t & 3) * 16;
  int j = j0 + jr;
  if (j < Ntrain) {
    const float4* src = (const float4*)(W + (size_t)j * ODIM);
    #pragma unroll
    for (int q = 0; q < 4; ++q) {
      float4 u = src[(cg >> 2) + q];
      tile[jr][cg + q * 4 + 0] = u.x;
      tile[jr][cg + q * 4 + 1] = u.y;
      tile[jr][cg + q * 4 + 2] = u.z;
      tile[jr][cg + q * 4 + 3] = u.w;
    }
  } else {
    #pragma unroll
    for (int q = 0; q < 16; ++q) tile[jr][cg + q] = 0.0f;
  }
  __syncthreads();
  int v = t >> 2;
  int jc = (t & 3) * 16;
  __bf16 ob[16];
  #pragma unroll
  for (int q = 0; q < 16; ++q) ob[q] = (__bf16)tile[jc + q][v];
  __bf16* dst = Wt + (size_t)v * Npad + j0 + jc;
  *(bf16x8*)dst = *(bf16x8*)&ob[0];
  *(bf16x8*)(dst + 8) = *(bf16x8*)&ob[8];
}

// ---- Main fused kernel (S^T formulation, P chained in registers, all LDS-staged).
// grid(NS, 16), ns fastest; NS % 8 == 0 keeps same-chunk readers co-XCD (L2 reuse of T).
// LDS = 24.5 KB -> 6 blocks/CU when grid supplies them (NS=96 -> 1536 blocks).
// __launch_bounds__ 2nd arg stays 4: compiler naturally allocates ~64-80 VGPR;
// runtime occupancy is then LDS-capped at 6 blocks/CU. (256,6) forces spills — round 4.
template <int NS, bool ATOMIC>
__global__ __launch_bounds__(256, 4) void rbf_main(
    const __bf16* __restrict__ Fb, const __bf16* __restrict__ Tb,
    const __bf16* __restrict__ Wt, const float* __restrict__ t2g,
    const float* __restrict__ x2g, float* __restrict__ outOrPart,
    int nRows, int Npad, int nChunks) {
  __shared__ __bf16 sT[BN * DIM];   // 16 KB, XOR-swizzled 16B granules
  __shared__ __bf16 sW[ODIM * BN];  // 8 KB, XOR-swizzled 16B granules
  __shared__ float st2[BN];

  const int tid = threadIdx.x;
  const int wave = tid >> 6;
  const int lane = tid & 63;
  const int l16 = lane & 15;
  const int g4 = lane >> 4;

  const int ns = (int)blockIdx.x;  // 0..NS-1
  const int mb = (int)blockIdx.y;  // 0..15

  constexpr float KNEG2 = (float)(-2.0 * C2D);

  // ---- chunk-invariant LDS read offsets (ds_read gets reg + imm form)
  int aOff[4];  // sT A-frags: + mt*4096 imm
  #pragma unroll
  for (int ko = 0; ko < 4; ++ko) aOff[ko] = l16 * 256 + (((ko * 4 + g4) ^ l16) << 4);
  int wOff[4];  // sW B-frags: + vi*2048 imm
  #pragma unroll
  for (int mt = 0; mt < 4; ++mt)
    wOff[mt] = l16 * 128 + ((g4 & 1) << 3) + ((((2 * mt + (g4 >> 1)) ^ (l16 & 7))) << 4);

  // ---- chunk-invariant staging offsets; global bases advance by stride per chunk
  int tGOff[4], ldsOffT[4];
  #pragma unroll
  for (int i = 0; i < 4; ++i) {
    int off = i * 4096 + wave * 1024;
    int loff = off + lane * 16;
    int row = loff >> 8;
    int gran = (loff >> 4) & 15;
    ldsOffT[i] = off;
    tGOff[i] = row * 256 + ((gran ^ (row & 15)) << 4);
  }
  int wGOff[2], ldsOffW[2];
  #pragma unroll
  for (int i = 0; i < 2; ++i) {
    int off = i * 4096 + wave * 1024;
    int loff = off + lane * 16;
    int v = loff >> 7;
    int gran = (loff >> 4) & 7;
    ldsOffW[i] = off;
    wGOff[i] = v * (Npad * 2) + ((gran ^ (v & 7)) << 4);
  }
  const char* gTbase = (const char*)Tb + (size_t)ns * (BN * 256);
  const char* gWbase = (const char*)Wt + (size_t)ns * (BN * 2);
  const char* gt2 = (const char*)(t2g) + (size_t)ns * (BN * 4) + lane * 4;
  const size_t strT = (size_t)NS * (BN * 256);
  const size_t strW = (size_t)NS * (BN * 2);
  const size_t str2 = (size_t)NS * (BN * 4);

  // F fragments (chunk-invariant)
  bf16x8 bF[2][4];
  #pragma unroll
  for (int nf = 0; nf < 2; ++nf)
    #pragma unroll
    for (int ko = 0; ko < 4; ++ko)
      bF[nf][ko] = *(const bf16x8*)(Fb + ((size_t)(mb * BM + wave * 32 + nf * 16 + l16)) * DIM +
                                    ko * 32 + g4 * 8);
  float x2v[2];
  #pragma unroll
  for (int nf = 0; nf < 2; ++nf)
    x2v[nf] = x2g[mb * BM + wave * 32 + nf * 16 + l16];

  f32x4 zero4 = {0.0f, 0.0f, 0.0f, 0.0f};
  f32x4 oacc[2][4];
  #pragma unroll
  for (int nf = 0; nf < 2; ++nf)
    #pragma unroll
    for (int vi = 0; vi < 4; ++vi) oacc[nf][vi] = zero4;

  for (int c = ns; c < nChunks; c += NS) {
    #pragma unroll
    for (int i = 0; i < 4; ++i) async_copy16(gTbase + tGOff[i], (char*)sT + ldsOffT[i]);
    #pragma unroll
    for (int i = 0; i < 2; ++i) async_copy16(gWbase + wGOff[i], (char*)sW + ldsOffW[i]);
    if (wave == 0) async_copy4(gt2, (char*)st2);
    gTbase += strT;
    gWbase += strW;
    gt2 += str2;
    __syncthreads();

    // S^T per 16-train tile mt, elementwise, pack to K16 A-frags in registers
    uint2 pk[4][2];
    #pragma unroll
    for (int mt = 0; mt < 4; ++mt) {
      f32x4 s0 = zero4, s1 = zero4;
      #pragma unroll
      for (int ko = 0; ko < 4; ++ko) {
        bf16x8 a = *(const bf16x8*)((const char*)sT + aOff[ko] + mt * 4096);
        s0 = MFMA_K32(a, bF[0][ko], s0);
        s1 = MFMA_K32(a, bF[1][ko], s1);
      }
      f32x4 t2v = *(const f32x4*)&st2[mt * 16 + g4 * 4];
      float kv0[4], kv1[4];
      #pragma unroll
      for (int r = 0; r < 4; ++r) {
        float d20 = __builtin_fmaf(KNEG2, s0[r], t2v[r] + x2v[0]);
        float d21 = __builtin_fmaf(KNEG2, s1[r], t2v[r] + x2v[1]);
        kv0[r] = __builtin_amdgcn_exp2f(-__builtin_amdgcn_sqrtf(d20));
        kv1[r] = __builtin_amdgcn_exp2f(-__builtin_amdgcn_sqrtf(d21));
      }
      pk[mt][0] = make_uint2(pack_bf16(kv0[0], kv0[1]), pack_bf16(kv0[2], kv0[3]));
      pk[mt][1] = make_uint2(pack_bf16(kv1[0], kv1[1]), pack_bf16(kv1[2], kv1[3]));
    }

    // O += P·W via K16 MFMA, A from registers, B from sW
    #pragma unroll
    for (int vi = 0; vi < 4; ++vi) {
      #pragma unroll
      for (int mt = 0; mt < 4; ++mt) {
        bf16x4 wf = *(const bf16x4*)((const char*)sW + wOff[mt] + vi * 2048);
        oacc[0][vi] = MFMA_K16(__builtin_bit_cast(bf16x4, pk[mt][0]), wf, oacc[0][vi]);
        oacc[1][vi] = MFMA_K16(__builtin_bit_cast(bf16x4, pk[mt][1]), wf, oacc[1][vi]);
      }
    }
    __syncthreads();  // protect sT/sW from next chunk's staging
  }

  if (ATOMIC) {
    float* out = outOrPart;
    #pragma unroll
    for (int nf = 0; nf < 2; ++nf)
      #pragma unroll
      for (int vi = 0; vi < 4; ++vi)
        #pragma unroll
        for (int r = 0; r < 4; ++r) {
          int row = mb * BM + wave * 32 + nf * 16 + g4 * 4 + r;
          int col = vi * 16 + l16;
          atomicAdd(&out[(size_t)row * ODIM + col], oacc[nf][vi][r]);
        }
  } else {
    float* dst = outOrPart + (size_t)ns * (size_t)nRows * ODIM;
    #pragma unroll
    for (int nf = 0; nf < 2; ++nf)
      #pragma unroll
      for (int vi = 0; vi < 4; ++vi)
        #pragma unroll
        for (int r = 0; r < 4; ++r) {
          int row = mb * BM + wave * 32 + nf * 16 + g4 * 4 + r;
          int col = vi * 16 + l16;
          dst[(size_t)row * ODIM + col] = oacc[nf][vi][r];
        }
  }
}

template <int NS>
__global__ void reduce_parts(const float4* __restrict__ part, float4* __restrict__ out,
                             int total4) {
  int i = (int)blockIdx.x * blockDim.x + threadIdx.x;
  if (i >= total4) return;
  float4 s = make_float4(0.0f, 0.0f, 0.0f, 0.0f);
  #pragma unroll
  for (int sp = 0; sp < NS; ++sp) {
    float4 v = part[(size_t)sp * total4 + i];
    s.x += v.x; s.y += v.y; s.z += v.z; s.w += v.w;
  }
  out[i] = s;
}

extern "C" void kernel_launch(void* const* d_in, const int* in_sizes, int n_in,
                              void* d_out, int out_size, void* d_ws, size_t ws_size,
                              hipStream_t stream) {
  (void)n_in;
  const float* features = (const float*)d_in[0];
  const float* train = (const float*)d_in[1];
  const float* weights = (const float*)d_in[2];
  float* out = (float*)d_out;

  const int n = in_sizes[0] / DIM;        // 2048
  const int N = in_sizes[1] / DIM;        // 50000
  const int Npad = ((N + 63) / 64) * 64;  // 50048
  const int nChunks = Npad / 64;          // 782

  size_t off = 0;
  auto alloc = [&](size_t bytes) {
    size_t o = off;
    off = (off + bytes + 255) & ~(size_t)255;
    return o;
  };
  size_t oT = alloc((size_t)Npad * DIM * 2);
  size_t oW = alloc((size_t)ODIM * Npad * 2);
  size_t oF = alloc((size_t)n * DIM * 2);
  size_t ot2 = alloc((size_t)Npad * 4);
  size_t ox2 = alloc((size_t)n * 4);
  size_t bufEnd = off;
  size_t oPart = alloc(0);

  char* ws = (char*)d_ws;
  __bf16* Tb = (__bf16*)(ws + oT);
  __bf16* Wt = (__bf16*)(ws + oW);
  __bf16* Fb = (__bf16*)(ws + oF);
  float* t2 = (float*)(ws + ot2);
  float* x2 = (float*)(ws + ox2);
  float* part = (float*)(ws + oPart);

  const int tB = Npad / 4;
  const int fB = n / 4;
  const int wB = Npad / 64;
  prep_all<<<tB + fB + wB, 256, 0, stream>>>(train, Tb, t2, features, Fb, x2, weights, Wt,
                                             N, Npad, n, tB, fB, (float)C2D);

  const int mBlocks = n / BM;  // 16
  const int total4 = n * ODIM / 4;
  const size_t partBytes = (size_t)n * ODIM * 4;

  if (ws_size >= bufEnd + 96 * partBytes) {
    rbf_main<96, false><<<dim3(96, mBlocks), 256, 0, stream>>>(Fb, Tb, Wt, t2, x2, part, n,
                                                               Npad, nChunks);
    reduce_parts<96><<<(total4 + 255) / 256, 256, 0, stream>>>((const float4*)part,
                                                               (float4*)out, total4);
  } else if (ws_size >= bufEnd + 32 * partBytes) {
    rbf_main<32, false><<<dim3(32, mBlocks), 256, 0, stream>>>(Fb, Tb, Wt, t2, x2, part, n,
                                                               Npad, nChunks);
    reduce_parts<32><<<(total4 + 255) / 256, 256, 0, stream>>>((const float4*)part,
                                                               (float4*)out, total4);
  } else {
    hipMemsetAsync(d_out, 0, (size_t)out_size * sizeof(float), stream);
    rbf_main<96, true><<<dim3(96, mBlocks), 256, 0, stream>>>(Fb, Tb, Wt, t2, x2, out, n,
                                                              Npad, nChunks);
  }
}